// Round 1
// baseline (3178.313 us; speedup 1.0000x reference)
//
#include <hip/hip_runtime.h>
#include <cstddef>

// Problem constants (fixed by setup_inputs)
#define BH   16      // b*h = 2*8
#define LSEQ 4096
#define DK   128
#define DV   128
#define C    32      // chunk size
#define NCH  128     // LSEQ / C
#define LP   129     // LDS pitch for 128-wide rows (odd -> conflict-free)
#define DVB  32      // dv block per scan workgroup
#define NDVB 4       // DV / DVB

// ---------------------------------------------------------------------------
// Kernel 1: per-chunk precompute.
// One block per (bh, chunk). Computes kn = l2norm(k), kb = kn*beta, vb = v*beta,
// T = (I + strict_lower(kb @ kn^T))^{-1}, then u = T@vb, w = T@kb -> workspace.
// ---------------------------------------------------------------------------
__global__ __launch_bounds__(256) void k_prep(const float* __restrict__ K,
                                              const float* __restrict__ V,
                                              const float* __restrict__ Beta,
                                              float* __restrict__ Wws,
                                              float* __restrict__ Uws) {
    __shared__ float kn[C * LP];
    __shared__ float kb[C * LP];
    __shared__ float vb[C * LP];
    __shared__ float A[C * 33];
    __shared__ float sbeta[C];
    __shared__ float rnorm[C];

    const int t = threadIdx.x;
    const int blk = blockIdx.x;          // bh*NCH + chunk
    const int bh = blk >> 7;
    const int cid = blk & (NCH - 1);
    const size_t base = ((size_t)bh * LSEQ + (size_t)cid * C) * DK;

    if (t < C) sbeta[t] = Beta[(size_t)bh * LSEQ + cid * C + t];
    for (int e = t; e < C * DK; e += 256) {
        int r = e >> 7, c = e & 127;
        kn[r * LP + c] = K[base + e];
        vb[r * LP + c] = V[base + e];
    }
    __syncthreads();

    // row norms of k (8 threads per row)
    {
        int r = t >> 3, s = t & 7;
        float ss = 0.f;
        for (int c = s * 16; c < s * 16 + 16; ++c) {
            float x = kn[r * LP + c];
            ss += x * x;
        }
        ss += __shfl_xor(ss, 1);
        ss += __shfl_xor(ss, 2);
        ss += __shfl_xor(ss, 4);
        if (s == 0) rnorm[r] = rsqrtf(ss + 1e-6f);
    }
    __syncthreads();

    // normalize k, build kb and vb
    for (int e = t; e < C * DK; e += 256) {
        int r = e >> 7, c = e & 127;
        float x = kn[r * LP + c] * rnorm[r];
        kn[r * LP + c] = x;
        kb[r * LP + c] = x * sbeta[r];
        vb[r * LP + c] *= sbeta[r];
    }
    __syncthreads();

    // A = -(kb @ kn^T), strict lower only
    for (int e = t; e < C * C; e += 256) {
        int i = e >> 5, j = e & 31;
        float s = 0.f;
        if (i > j) {
            for (int d = 0; d < DK; ++d) s -= kb[i * LP + d] * kn[j * LP + d];
        }
        A[i * 33 + j] = s;
    }
    __syncthreads();

    // forward substitution: row i gets += A[i,:] @ A[:, :i]  (old row i values)
    for (int i = 1; i < C; ++i) {
        float upd = 0.f;
        if (t < i) {
            for (int kk = t + 1; kk < i; ++kk) upd += A[i * 33 + kk] * A[kk * 33 + t];
        }
        __syncthreads();
        if (t < i) A[i * 33 + t] += upd;
        __syncthreads();
    }
    if (t < C) A[t * 33 + t] += 1.f;  // T = A + I
    __syncthreads();

    // u = T @ vb ; w = T @ kb   (T lower-triangular incl diag)
    for (int e = t; e < C * DK; e += 256) {
        int i = e >> 7, c = e & 127;
        float su = 0.f, sw = 0.f;
        for (int j = 0; j <= i; ++j) {
            float a = A[i * 33 + j];
            su += a * vb[j * LP + c];
            sw += a * kb[j * LP + c];
        }
        Uws[base + e] = su;
        Wws[base + e] = sw;
    }
}

// ---------------------------------------------------------------------------
// Kernel 2: sequential chunk scan, split along dv into NDVB blocks.
// blockIdx.x = db*16 + bh  (so the 4 sibling dv-blocks of one bh share an XCD).
// State S[DK][DVB] in LDS. Per chunk:
//   attn = strict_lower_incl_diag(qn @ kn^T)
//   u' = u - w @ S
//   o  = qn @ S + attn @ u'
//   S += kn^T @ u'
// ---------------------------------------------------------------------------
__global__ __launch_bounds__(512) void k_scan(const float* __restrict__ Q,
                                              const float* __restrict__ K,
                                              const float* __restrict__ Wws,
                                              const float* __restrict__ Uws,
                                              float* __restrict__ Out,
                                              float* __restrict__ Sout) {
    __shared__ float qn[C * LP];
    __shared__ float kn[C * LP];
    __shared__ float wS[C * LP];
    __shared__ float S[DK * 33];
    __shared__ float up[C * 33];
    __shared__ float attn[C * 33];
    __shared__ float rnq[C];
    __shared__ float rnk[C];

    const int t = threadIdx.x;
    const int db = blockIdx.x >> 4;     // dv block 0..3
    const int bh = blockIdx.x & 15;

    // zero state
    for (int e = t; e < DK * DVB; e += 512) {
        int d = e >> 5, c = e & 31;
        S[d * 33 + c] = 0.f;
    }
    __syncthreads();

    for (int cid = 0; cid < NCH; ++cid) {
        const size_t base = ((size_t)bh * LSEQ + (size_t)cid * C) * DK;

        // stage q, k, w
        for (int e = t; e < C * DK; e += 512) {
            int r = e >> 7, c = e & 127;
            qn[r * LP + c] = Q[base + e];
            kn[r * LP + c] = K[base + e];
            wS[r * LP + c] = Wws[base + e];
        }
        __syncthreads();

        // l2-normalize q and k rows (16 threads per row)
        {
            int r = t >> 4, s = t & 15;
            float sq = 0.f, sk = 0.f;
            for (int c = s * 8; c < s * 8 + 8; ++c) {
                float a = qn[r * LP + c];
                sq += a * a;
                float b = kn[r * LP + c];
                sk += b * b;
            }
            for (int m = 1; m < 16; m <<= 1) {
                sq += __shfl_xor(sq, m);
                sk += __shfl_xor(sk, m);
            }
            if (s == 0) {
                rnq[r] = rsqrtf(sq + 1e-6f);
                rnk[r] = rsqrtf(sk + 1e-6f);
            }
        }
        __syncthreads();
        for (int e = t; e < C * DK; e += 512) {
            int r = e >> 7, c = e & 127;
            qn[r * LP + c] *= rnq[r];
            kn[r * LP + c] *= rnk[r];
        }
        __syncthreads();

        // attn = lower(qn @ kn^T) incl diag
        for (int e = t; e < C * C; e += 512) {
            int i = e >> 5, j = e & 31;
            float s = 0.f;
            if (j <= i) {
                for (int d = 0; d < DK; ++d) s += qn[i * LP + d] * kn[j * LP + d];
            }
            attn[i * 33 + j] = s;
        }
        // u' = u - w @ S
        for (int e = t; e < C * DVB; e += 512) {
            int i = e >> 5, c = e & 31;
            float s = Uws[base + i * DK + db * DVB + c];
            for (int d = 0; d < DK; ++d) s -= wS[i * LP + d] * S[d * 33 + c];
            up[i * 33 + c] = s;
        }
        __syncthreads();

        // o = qn @ S + attn @ u'
        for (int e = t; e < C * DVB; e += 512) {
            int i = e >> 5, c = e & 31;
            float s = 0.f;
            for (int d = 0; d < DK; ++d) s += qn[i * LP + d] * S[d * 33 + c];
            for (int j = 0; j <= i; ++j) s += attn[i * 33 + j] * up[j * 33 + c];
            Out[base + i * DK + db * DVB + c] = s;
        }
        __syncthreads();  // all reads of old S done before update

        // S += kn^T @ u'
        for (int e = t; e < DK * DVB; e += 512) {
            int d = e >> 5, c = e & 31;
            float s = 0.f;
            for (int i = 0; i < C; ++i) s += kn[i * LP + d] * up[i * 33 + c];
            S[d * 33 + c] += s;
        }
        __syncthreads();  // S update + staging reads done before next chunk load
    }

    // final state output: (bh, dk, dv)
    for (int e = t; e < DK * DVB; e += 512) {
        int d = e >> 5, c = e & 31;
        Sout[(size_t)bh * DK * DV + (size_t)d * DV + db * DVB + c] = S[d * 33 + c];
    }
}

extern "C" void kernel_launch(void* const* d_in, const int* in_sizes, int n_in,
                              void* d_out, int out_size, void* d_ws, size_t ws_size,
                              hipStream_t stream) {
    const float* Q    = (const float*)d_in[0];
    const float* K    = (const float*)d_in[1];
    const float* V    = (const float*)d_in[2];
    const float* Beta = (const float*)d_in[3];

    float* Out  = (float*)d_out;
    float* Sout = Out + (size_t)BH * LSEQ * DV;   // final-state output follows o

    float* Wws = (float*)d_ws;
    float* Uws = Wws + (size_t)BH * LSEQ * DK;    // 33.5 MB each, fp32

    hipLaunchKernelGGL(k_prep, dim3(BH * NCH), dim3(256), 0, stream,
                       K, V, Beta, Wws, Uws);
    hipLaunchKernelGGL(k_scan, dim3(BH * NDVB), dim3(512), 0, stream,
                       Q, K, Wws, Uws, Out, Sout);
}

// Round 4
// 770.478 us; speedup vs baseline: 4.1251x; 4.1251x over previous
//
#include <hip/hip_runtime.h>
#include <cstddef>

// Problem constants (fixed by setup_inputs)
#define BH   16      // b*h = 2*8
#define LSEQ 4096
#define DK   128
#define DV   128
#define C    32      // chunk size
#define NCH  128     // LSEQ / C
#define DVB  32      // dv block per scan workgroup
#define NDVB 4       // DV / DVB

#define PK   136     // bf16-plane pitch for [32][128] arrays (mult of 8, non-pow2)
#define PC   40      // bf16-plane pitch for [*][32] arrays  (mult of 8, non-pow2)
#define LPP  132     // fp32 pitch (prep), mult of 4 for float4
#define AP   36      // pitch of 32x32 fp32 matrix A (prep)

typedef __attribute__((ext_vector_type(4))) float f32x4;
typedef __attribute__((ext_vector_type(8))) short short8;

// ---- split-bf16: x ~= hi + lo, each bf16 (rne). Returns (hi<<16)|lo packed. ----
__device__ inline unsigned split_bf16(float x) {
    unsigned u = __builtin_bit_cast(unsigned, x);
    unsigned r = u + 0x7fffu + ((u >> 16) & 1u);
    unsigned h = r >> 16;
    float hf = __builtin_bit_cast(float, r & 0xffff0000u);
    float res = x - hf;
    unsigned u2 = __builtin_bit_cast(unsigned, res);
    unsigned r2 = u2 + 0x7fffu + ((u2 >> 16) & 1u);
    return (h << 16) | (r2 >> 16);
}

__device__ inline void split8_store(short* Ph, short* Pl, int idx, f32x4 a, f32x4 b, float s) {
    short8 h, l;
#pragma unroll
    for (int i = 0; i < 4; ++i) {
        unsigned p = split_bf16(a[i] * s);
        h[i] = (short)(p >> 16);
        l[i] = (short)(p & 0xffffu);
    }
#pragma unroll
    for (int i = 0; i < 4; ++i) {
        unsigned p = split_bf16(b[i] * s);
        h[4 + i] = (short)(p >> 16);
        l[4 + i] = (short)(p & 0xffffu);
    }
    *(short8*)(Ph + idx) = h;
    *(short8*)(Pl + idx) = l;
}

// frag load from a row-major [outdim][K] bf16 plane:
// lane holds elems [row0 + (lane&15)][k0 + (lane>>4)*8 + j], j=0..7  (one ds_read_b128)
__device__ inline short8 fld(const short* P, int row0, int pitch, int k0, int lane) {
    return *(const short8*)(P + (row0 + (lane & 15)) * pitch + k0 + ((lane >> 4) << 3));
}

__device__ inline f32x4 mf(short8 a, short8 b, f32x4 c) {
    return __builtin_amdgcn_mfma_f32_16x16x32_bf16(a, b, c, 0, 0, 0);
}
__device__ inline f32x4 mf3(short8 ah, short8 al, short8 bh, short8 bl, f32x4 c) {
    c = mf(ah, bh, c);
    c = mf(ah, bl, c);
    c = mf(al, bh, c);
    return c;
}

// ---------------------------------------------------------------------------
// Kernel 1: per-chunk precompute (fp32, register-tiled).
// kn = l2norm(k); kb = kn*beta; vb = v*beta;
// T = (I + strict_lower(kb@kn^T))^{-1}; u = T@vb; w = T@kb  -> workspace.
// ---------------------------------------------------------------------------
__global__ __launch_bounds__(256) void k_prep(const float* __restrict__ K,
                                              const float* __restrict__ V,
                                              const float* __restrict__ Beta,
                                              float* __restrict__ Wws,
                                              float* __restrict__ Uws) {
    __shared__ float kn[C * LPP];
    __shared__ float kb[C * LPP];
    __shared__ float vb[C * LPP];
    __shared__ float A[C * AP];
    __shared__ float sbeta[C];
    __shared__ float rnorm[C];

    const int t = threadIdx.x;
    const int blk = blockIdx.x;
    const int bh = blk >> 7;
    const int cid = blk & (NCH - 1);
    const size_t base = ((size_t)bh * LSEQ + (size_t)cid * C) * DK;

    if (t < C) sbeta[t] = Beta[(size_t)bh * LSEQ + cid * C + t];
#pragma unroll
    for (int s = 0; s < 4; ++s) {
        int idx = t + 256 * s;             // float4 slot 0..1023
        int r = idx >> 5, c4 = (idx & 31) * 4;
        *(f32x4*)(kn + r * LPP + c4) = *(const f32x4*)(K + base + r * DK + c4);
        *(f32x4*)(vb + r * LPP + c4) = *(const f32x4*)(V + base + r * DK + c4);
    }
    __syncthreads();

    {   // row norms of k (8 threads/row, 16 cols each)
        int r = t >> 3, s8 = t & 7;
        float ss = 0.f;
#pragma unroll
        for (int q = 0; q < 4; ++q) {
            f32x4 x = *(f32x4*)(kn + r * LPP + s8 * 16 + 4 * q);
            ss += x[0] * x[0] + x[1] * x[1] + x[2] * x[2] + x[3] * x[3];
        }
        ss += __shfl_xor(ss, 1);
        ss += __shfl_xor(ss, 2);
        ss += __shfl_xor(ss, 4);
        if (s8 == 0) rnorm[r] = rsqrtf(ss + 1e-6f);
    }
    __syncthreads();

#pragma unroll
    for (int s = 0; s < 4; ++s) {
        int idx = t + 256 * s;
        int r = idx >> 5, c4 = (idx & 31) * 4;
        float rn = rnorm[r], be = sbeta[r];
        f32x4 x = *(f32x4*)(kn + r * LPP + c4);
        x *= rn;
        *(f32x4*)(kn + r * LPP + c4) = x;
        *(f32x4*)(kb + r * LPP + c4) = x * be;
        f32x4 v = *(f32x4*)(vb + r * LPP + c4);
        *(f32x4*)(vb + r * LPP + c4) = v * be;
    }
    __syncthreads();

    {   // A = -(kb @ kn^T), strict lower; thread: row i, cols j0..j0+3
        int i = t >> 3, j0 = (t & 7) * 4;
        if (j0 < i) {
            f32x4 acc = {0.f, 0.f, 0.f, 0.f};
            for (int d = 0; d < DK; d += 4) {
                f32x4 a = *(f32x4*)(kb + i * LPP + d);
#pragma unroll
                for (int m = 0; m < 4; ++m) {
                    f32x4 b = *(f32x4*)(kn + (j0 + m) * LPP + d);
                    acc[m] -= a[0] * b[0] + a[1] * b[1] + a[2] * b[2] + a[3] * b[3];
                }
            }
#pragma unroll
            for (int m = 0; m < 4; ++m)
                if (j0 + m < i) A[i * AP + j0 + m] = acc[m];
        }
    }
    __syncthreads();

    // forward substitution, single wave (per-wave LDS ordering; reads of row i
    // precede writes of row i in program order within the wave).
    // NOTE: only strict-lower of A is initialized; substitution reads only
    // strict-lower entries. Diagonal must be ASSIGNED (=1), not accumulated.
    if (t < 64) {
        int j = t;
        for (int i = 1; i < C; ++i) {
            float upd = 0.f;
            if (j < i) {
                for (int kk = j + 1; kk < i; ++kk) upd += A[i * AP + kk] * A[kk * AP + j];
                A[i * AP + j] += upd;
            }
        }
        if (t < C) A[t * AP + t] = 1.f;   // T = A + I (diag was uninitialized)
    }
    __syncthreads();

    // u = T@vb ; w = T@kb  (lower-triangular apply, float4 over columns)
#pragma unroll
    for (int s = 0; s < 4; ++s) {
        int idx = t + 256 * s;
        int i = idx >> 5, c4 = (idx & 31) * 4;
        f32x4 au = {0.f, 0.f, 0.f, 0.f}, aw = {0.f, 0.f, 0.f, 0.f};
        for (int j = 0; j <= i; ++j) {
            float a = A[i * AP + j];
            au += a * *(f32x4*)(vb + j * LPP + c4);
            aw += a * *(f32x4*)(kb + j * LPP + c4);
        }
        *(f32x4*)(Uws + base + i * DK + c4) = au;
        *(f32x4*)(Wws + base + i * DK + c4) = aw;
    }
}

// ---------------------------------------------------------------------------
// Kernel 2: sequential chunk scan, MFMA (split-bf16), dv split into 4 blocks.
// blockIdx = db*16 + bh (siblings land on the same XCD for L2 sharing).
// 512 threads = 8 waves. S^T kept as persistent fp32 MFMA accumulators.
// ---------------------------------------------------------------------------
__global__ __launch_bounds__(512, 1) void k_scan(const float* __restrict__ Q,
                                                 const float* __restrict__ K,
                                                 const float* __restrict__ Wws,
                                                 const float* __restrict__ Uws,
                                                 float* __restrict__ Out,
                                                 float* __restrict__ Sout) {
    __shared__ short qh[C * PK], ql[C * PK];
    __shared__ short kh[C * PK], kl[C * PK];
    __shared__ short wh[C * PK], wl[C * PK];
    __shared__ short STh[DVB * PK], STl[DVB * PK];   // S^T [dv][dk]
    __shared__ short kTh[DK * PC], kTl[DK * PC];     // k^T [dk][c]
    __shared__ short uTh[DVB * PC], uTl[DVB * PC];   // u'^T [dv][c]
    __shared__ short ath[C * PC], atl[C * PC];       // attn [ci][cj]

    const int t = threadIdx.x;
    const int lane = t & 63;
    const int wv = t >> 6;
    const int quad = (t >> 4) & 3;
    const int l15 = t & 15;
    const int db = blockIdx.x >> 4;
    const int bh = blockIdx.x & 15;

    const size_t bbase = (size_t)bh * LSEQ * DK;
    const int vcol = db * DVB;

    const int w2 = wv & 3;
    const int i0 = (w2 >> 1) * 16;     // tile row base (ci)
    const int c0 = (w2 & 1) * 16;      // tile col base (dv for waves 0-3, cj for 4-7)

    // persistent S^T accumulator tiles: 16 tiles (mt 0..1 over dv, nt 0..7 over dk)
    const int ntile = (wv < 4) ? 1 : 3;
    const int tbase = (wv < 4) ? wv : 4 + 3 * (wv - 4);
    f32x4 accS[3];
#pragma unroll
    for (int i = 0; i < 3; ++i) accS[i] = (f32x4){0.f, 0.f, 0.f, 0.f};

    for (int e = t; e < DVB * PK; e += 512) { STh[e] = 0; STl[e] = 0; }

    // register prefetch: each thread owns elems [8t, 8t+8) of each [32][128] array
    f32x4 pq0, pq1, pk0, pk1, pw0, pw1;
    float pu[4] = {0.f, 0.f, 0.f, 0.f};
    const int srow = t >> 4, scol = (t & 15) * 8;

    {
        const size_t cb = bbase;
        pq0 = *(const f32x4*)(Q + cb + 8 * t);   pq1 = *(const f32x4*)(Q + cb + 8 * t + 4);
        pk0 = *(const f32x4*)(K + cb + 8 * t);   pk1 = *(const f32x4*)(K + cb + 8 * t + 4);
        pw0 = *(const f32x4*)(Wws + cb + 8 * t); pw1 = *(const f32x4*)(Wws + cb + 8 * t + 4);
        if (wv < 4) {
#pragma unroll
            for (int r = 0; r < 4; ++r)
                pu[r] = Uws[cb + (size_t)(i0 + quad * 4 + r) * DK + vcol + c0 + l15];
        }
    }

    // normalize q,k rows in-register (16-lane groups), split to bf16 planes
    auto stage_planes = [&]() {
        float ssq = 0.f, ssk = 0.f;
#pragma unroll
        for (int i = 0; i < 4; ++i) {
            ssq += pq0[i] * pq0[i] + pq1[i] * pq1[i];
            ssk += pk0[i] * pk0[i] + pk1[i] * pk1[i];
        }
#pragma unroll
        for (int m = 1; m < 16; m <<= 1) {
            ssq += __shfl_xor(ssq, m);
            ssk += __shfl_xor(ssk, m);
        }
        float rq = rsqrtf(ssq + 1e-6f), rk = rsqrtf(ssk + 1e-6f);
        int idx = srow * PK + scol;
        split8_store(qh, ql, idx, pq0, pq1, rq);
        split8_store(kh, kl, idx, pk0, pk1, rk);
        split8_store(wh, wl, idx, pw0, pw1, 1.f);
    };

    stage_planes();
    __syncthreads();

    for (int cid = 0; cid < NCH; ++cid) {
        float uc[4] = {pu[0], pu[1], pu[2], pu[3]};

        if (cid + 1 < NCH) {   // prefetch next chunk
            const size_t cb = bbase + (size_t)(cid + 1) * C * DK;
            pq0 = *(const f32x4*)(Q + cb + 8 * t);   pq1 = *(const f32x4*)(Q + cb + 8 * t + 4);
            pk0 = *(const f32x4*)(K + cb + 8 * t);   pk1 = *(const f32x4*)(K + cb + 8 * t + 4);
            pw0 = *(const f32x4*)(Wws + cb + 8 * t); pw1 = *(const f32x4*)(Wws + cb + 8 * t + 4);
            if (wv < 4) {
#pragma unroll
                for (int r = 0; r < 4; ++r)
                    pu[r] = Uws[cb + (size_t)(i0 + quad * 4 + r) * DK + vcol + c0 + l15];
            }
        }

        // ---- stage 1: u' (waves 0-3), attn (waves 4-7), k^T build (all) ----
        if (wv < 4) {
            f32x4 acc = {-uc[0], -uc[1], -uc[2], -uc[3]};   // acc = w@S - u = -u'
#pragma unroll
            for (int ks = 0; ks < DK; ks += 32)
                acc = mf3(fld(wh, i0, PK, ks, lane), fld(wl, i0, PK, ks, lane),
                          fld(STh, c0, PK, ks, lane), fld(STl, c0, PK, ks, lane), acc);
#pragma unroll
            for (int r = 0; r < 4; ++r) {
                unsigned p = split_bf16(-acc[r]);
                int idx = (c0 + l15) * PC + i0 + quad * 4 + r;
                uTh[idx] = (short)(p >> 16);
                uTl[idx] = (short)(p & 0xffffu);
            }
        } else {
            f32x4 acc = {0.f, 0.f, 0.f, 0.f};
#pragma unroll
            for (int ks = 0; ks < DK; ks += 32)
                acc = mf3(fld(qh, i0, PK, ks, lane), fld(ql, i0, PK, ks, lane),
                          fld(kh, c0, PK, ks, lane), fld(kl, c0, PK, ks, lane), acc);
#pragma unroll
            for (int r = 0; r < 4; ++r) {
                int row = i0 + quad * 4 + r, col = c0 + l15;
                float v = (col <= row) ? acc[r] : 0.f;   // causal (diag kept)
                unsigned p = split_bf16(v);
                ath[row * PC + col] = (short)(p >> 16);
                atl[row * PC + col] = (short)(p & 0xffffu);
            }
        }
        {   // k^T [dk][c] from kh/kl rows
            int c = t & 31, seg = t >> 5;
            short8 vh = *(const short8*)(kh + c * PK + 8 * seg);
            short8 vl = *(const short8*)(kl + c * PK + 8 * seg);
#pragma unroll
            for (int i = 0; i < 8; ++i) {
                kTh[(8 * seg + i) * PC + c] = vh[i];
                kTl[(8 * seg + i) * PC + c] = vl[i];
            }
        }
        __syncthreads();

        // ---- stage 2: o (waves 0-3) + S^T accumulate (all) ----
        if (wv < 4) {
            f32x4 acc = {0.f, 0.f, 0.f, 0.f};
#pragma unroll
            for (int ks = 0; ks < DK; ks += 32)
                acc = mf3(fld(qh, i0, PK, ks, lane), fld(ql, i0, PK, ks, lane),
                          fld(STh, c0, PK, ks, lane), fld(STl, c0, PK, ks, lane), acc);
            acc = mf3(fld(ath, i0, PC, 0, lane), fld(atl, i0, PC, 0, lane),
                      fld(uTh, c0, PC, 0, lane), fld(uTl, c0, PC, 0, lane), acc);
            const size_t ob = bbase + (size_t)cid * C * DK;
#pragma unroll
            for (int r = 0; r < 4; ++r)
                Out[ob + (size_t)(i0 + quad * 4 + r) * DK + vcol + c0 + l15] = acc[r];
        }
#pragma unroll
        for (int tt = 0; tt < 3; ++tt) {
            if (tt < ntile) {
                int idx = tbase + tt, mt = idx >> 3, nt = idx & 7;
                accS[tt] = mf3(fld(uTh, mt * 16, PC, 0, lane), fld(uTl, mt * 16, PC, 0, lane),
                               fld(kTh, nt * 16, PC, 0, lane), fld(kTl, nt * 16, PC, 0, lane),
                               accS[tt]);
            }
        }
        __syncthreads();

        // ---- stage 3: rewrite S planes; write next chunk's staged planes ----
#pragma unroll
        for (int tt = 0; tt < 3; ++tt) {
            if (tt < ntile) {
                int idx = tbase + tt, mt = idx >> 3, nt = idx & 7;
#pragma unroll
                for (int r = 0; r < 4; ++r) {
                    unsigned p = split_bf16(accS[tt][r]);
                    int o = (mt * 16 + quad * 4 + r) * PK + nt * 16 + l15;
                    STh[o] = (short)(p >> 16);
                    STl[o] = (short)(p & 0xffffu);
                }
            }
        }
        if (cid + 1 < NCH) stage_planes();
        __syncthreads();
    }

    // final state: Sout[bh][dk][dv]
#pragma unroll
    for (int tt = 0; tt < 3; ++tt) {
        if (tt < ntile) {
            int idx = tbase + tt, mt = idx >> 3, nt = idx & 7;
#pragma unroll
            for (int r = 0; r < 4; ++r)
                Sout[(size_t)bh * DK * DV + (size_t)(nt * 16 + l15) * DV + vcol + mt * 16 +
                     quad * 4 + r] = accS[tt][r];
        }
    }
}

extern "C" void kernel_launch(void* const* d_in, const int* in_sizes, int n_in,
                              void* d_out, int out_size, void* d_ws, size_t ws_size,
                              hipStream_t stream) {
    const float* Q    = (const float*)d_in[0];
    const float* K    = (const float*)d_in[1];
    const float* V    = (const float*)d_in[2];
    const float* Beta = (const float*)d_in[3];

    float* Out  = (float*)d_out;
    float* Sout = Out + (size_t)BH * LSEQ * DV;

    float* Wws = (float*)d_ws;
    float* Uws = Wws + (size_t)BH * LSEQ * DK;

    hipLaunchKernelGGL(k_prep, dim3(BH * NCH), dim3(256), 0, stream,
                       K, V, Beta, Wws, Uws);
    hipLaunchKernelGGL(k_scan, dim3(BH * NDVB), dim3(512), 0, stream,
                       Q, K, Wws, Uws, Out, Sout);
}

// Round 5
// 426.059 us; speedup vs baseline: 7.4598x; 1.8084x over previous
//
#include <hip/hip_runtime.h>
#include <cstddef>

// Problem constants (fixed by setup_inputs)
#define BH   16
#define LSEQ 4096
#define DK   128
#define DV   128
#define C    32
#define NCH  128
#define DVB  16      // dv per scan block
#define NDVB 8       // DV / DVB
#define PK   136     // bf16-plane pitch for [*][128] arrays (mult 8, non-pow2)
#define PC   40      // bf16-plane pitch for [*][32] arrays (mult 8, non-pow2)
#define AP   33      // fp32 pitch for 32x32 A (prep)

typedef __attribute__((ext_vector_type(4))) float f32x4;
typedef __attribute__((ext_vector_type(8))) short short8;
typedef __attribute__((ext_vector_type(4))) short s16x4;
typedef __attribute__((ext_vector_type(4))) unsigned u32x4;

// split-bf16: x ~= hi + lo, each bf16 (rne). Returns (hi<<16)|lo.
__device__ inline unsigned split_bf16(float x) {
    unsigned u = __builtin_bit_cast(unsigned, x);
    unsigned r = u + 0x7fffu + ((u >> 16) & 1u);
    unsigned h = r >> 16;
    float hf = __builtin_bit_cast(float, r & 0xffff0000u);
    float res = x - hf;
    unsigned u2 = __builtin_bit_cast(unsigned, res);
    unsigned r2 = u2 + 0x7fffu + ((u2 >> 16) & 1u);
    return (h << 16) | (r2 >> 16);
}
__device__ inline short hi_bf16(float x) {   // rne round to bf16
    unsigned u = __builtin_bit_cast(unsigned, x);
    return (short)((u + 0x7fffu + ((u >> 16) & 1u)) >> 16);
}
__device__ inline short trunc_bf16(float x) {  // exact (x already a bf16 value)
    return (short)(__builtin_bit_cast(unsigned, x) >> 16);
}

// MFMA fragment load: lane holds elems [row0+(lane&15)][k0 + (lane>>4)*8 + j]
__device__ inline short8 fld(const short* P, int row0, int pitch, int k0, int lane) {
    return *(const short8*)(P + (row0 + (lane & 15)) * pitch + k0 + ((lane >> 4) << 3));
}
__device__ inline f32x4 mf(short8 a, short8 b, f32x4 c) {
    return __builtin_amdgcn_mfma_f32_16x16x32_bf16(a, b, c, 0, 0, 0);
}
// identity B-frags for MFMA transpose: C[m][n]=Σ A[m][k] I[n][k]
__device__ inline void build_ifrags(int lane, short8& Iev, short8& Iod) {
    int n = lane & 15, q = lane >> 4;
#pragma unroll
    for (int j = 0; j < 8; ++j) {
        Iev[j] = (q * 8 + j == n)      ? (short)0x3F80 : (short)0;
        Iod[j] = (q * 8 + j == n + 16) ? (short)0x3F80 : (short)0;
    }
}

// ---------------------------------------------------------------------------
// Kernel 1: per-chunk precompute, MFMA-based.
//   kn = l2norm(k) -> packed planes to KnP (global)
//   G = kn@kn^T; A = strict_lower(-beta_i * G); T = (I+A)^{-1} (serial sub)
//   T' = T * diag(beta);  u = T'@v -> Uws (fp32);  w = T'@kn -> WP (packed)
// ---------------------------------------------------------------------------
__global__ __launch_bounds__(256) void k_prep(const float* __restrict__ K,
                                              const float* __restrict__ V,
                                              const float* __restrict__ Beta,
                                              unsigned* __restrict__ KnP,
                                              unsigned* __restrict__ WP,
                                              float* __restrict__ Uws) {
    __shared__ short knh[C * PK], knl[C * PK], vph[C * PK], vpl[C * PK];
    __shared__ short knTh[DK * PC], knTl[DK * PC], vTh[DK * PC], vTl[DK * PC];
    __shared__ short Th[C * PC], Tl[C * PC];
    __shared__ float A[C * AP];
    __shared__ float sbeta[C];

    const int t = threadIdx.x, lane = t & 63, wv = t >> 6;
    const int quad = (t >> 4) & 3, l15 = t & 15;
    const int bhi = blockIdx.x >> 7, cid = blockIdx.x & 127;
    const size_t base = ((size_t)bhi * LSEQ + (size_t)cid * C) * DK;

    short8 Iev, Iod;
    build_ifrags(lane, Iev, Iod);

    if (t < C) sbeta[t] = Beta[(size_t)bhi * LSEQ + cid * C + t];

    // load K,V: thread owns 16 consecutive elems (row sr, cols sc..sc+15)
    const int sr = t >> 3, sc = (t & 7) * 16;
    f32x4 kk[4], vv[4];
#pragma unroll
    for (int g = 0; g < 4; ++g) {
        kk[g] = *(const f32x4*)(K + base + 16 * t + 4 * g);
        vv[g] = *(const f32x4*)(V + base + 16 * t + 4 * g);
    }
    float ss = 0.f;
#pragma unroll
    for (int g = 0; g < 4; ++g)
        ss += kk[g][0]*kk[g][0] + kk[g][1]*kk[g][1] + kk[g][2]*kk[g][2] + kk[g][3]*kk[g][3];
    ss += __shfl_xor(ss, 1); ss += __shfl_xor(ss, 2); ss += __shfl_xor(ss, 4);
    const float rk = rsqrtf(ss + 1e-6f);

    // split kn (scaled) and v planes; Kn packed to global
    {
        unsigned pk[16];
        short8 h0, l0, h1, l1;
#pragma unroll
        for (int e = 0; e < 8; ++e) {
            unsigned p = split_bf16(kk[e >> 2][e & 3] * rk);
            pk[e] = p; h0[e] = (short)(p >> 16); l0[e] = (short)(p & 0xffffu);
        }
#pragma unroll
        for (int e = 0; e < 8; ++e) {
            unsigned p = split_bf16(kk[2 + (e >> 2)][e & 3] * rk);
            pk[8 + e] = p; h1[e] = (short)(p >> 16); l1[e] = (short)(p & 0xffffu);
        }
        *(short8*)(knh + sr * PK + sc) = h0;  *(short8*)(knh + sr * PK + sc + 8) = h1;
        *(short8*)(knl + sr * PK + sc) = l0;  *(short8*)(knl + sr * PK + sc + 8) = l1;
#pragma unroll
        for (int g = 0; g < 4; ++g) {
            u32x4 w4 = {pk[4*g], pk[4*g+1], pk[4*g+2], pk[4*g+3]};
            *(u32x4*)(KnP + base + 16 * t + 4 * g) = w4;
        }
        short8 vh0, vl0, vh1, vl1;
#pragma unroll
        for (int e = 0; e < 8; ++e) {
            unsigned p = split_bf16(vv[e >> 2][e & 3]);
            vh0[e] = (short)(p >> 16); vl0[e] = (short)(p & 0xffffu);
        }
#pragma unroll
        for (int e = 0; e < 8; ++e) {
            unsigned p = split_bf16(vv[2 + (e >> 2)][e & 3]);
            vh1[e] = (short)(p >> 16); vl1[e] = (short)(p & 0xffffu);
        }
        *(short8*)(vph + sr * PK + sc) = vh0;  *(short8*)(vph + sr * PK + sc + 8) = vh1;
        *(short8*)(vpl + sr * PK + sc) = vl0;  *(short8*)(vpl + sr * PK + sc + 8) = vl1;
    }
    __syncthreads();

    // G tile per wave -> A = strict_lower(-beta_i G), zeros elsewhere (full write)
    {
        const int ci0 = (wv >> 1) * 16, cj0 = (wv & 1) * 16;
        f32x4 acc = {0.f, 0.f, 0.f, 0.f};
#pragma unroll
        for (int ks = 0; ks < 4; ++ks) {
            short8 ah = fld(knh, ci0, PK, ks * 32, lane);
            short8 al = fld(knl, ci0, PK, ks * 32, lane);
            short8 bhf = fld(knh, cj0, PK, ks * 32, lane);
            short8 blf = fld(knl, cj0, PK, ks * 32, lane);
            acc = mf(ah, bhf, mf(ah, blf, mf(al, bhf, acc)));
        }
#pragma unroll
        for (int r = 0; r < 4; ++r) {
            int row = ci0 + quad * 4 + r, col = cj0 + l15;
            A[row * AP + col] = (row > col) ? -sbeta[row] * acc[r] : 0.f;
        }
    }
    __syncthreads();

    // MFMA transposes: kn,v planes -> knT,vT [128][PC]
    {
        const short* src = (wv == 0) ? knh : (wv == 1) ? knl : (wv == 2) ? vph : vpl;
        short* dst = (wv == 0) ? knTh : (wv == 1) ? knTl : (wv == 2) ? vTh : vTl;
#pragma unroll
        for (int half = 0; half < 2; ++half) {
            int c0 = half * 16;
#pragma unroll
            for (int ks = 0; ks < 4; ++ks) {
                short8 fr = fld(src, c0, PK, ks * 32, lane);
                f32x4 z = {0.f, 0.f, 0.f, 0.f};
                f32x4 cA = mf(fr, Iev, z);
                f32x4 cB = mf(fr, Iod, z);
                s16x4 sA, sB;
#pragma unroll
                for (int r = 0; r < 4; ++r) { sA[r] = trunc_bf16(cA[r]); sB[r] = trunc_bf16(cB[r]); }
                *(s16x4*)(dst + (ks * 32 + l15) * PC + c0 + quad * 4) = sA;
                *(s16x4*)(dst + (ks * 32 + 16 + l15) * PC + c0 + quad * 4) = sB;
            }
        }
    }
    __syncthreads();

    // forward substitution (wave 0; A upper triangle is zero so masks vanish)
    if (wv == 0 && lane < C) {
        const int j = lane;
        for (int i = 1; i < C; ++i) {
            float upd = 0.f;
            for (int kk2 = 1; kk2 < i; ++kk2) upd += A[i * AP + kk2] * A[kk2 * AP + j];
            if (j < i) A[i * AP + j] += upd;
        }
    }
    __syncthreads();

    // T' = (A + I) * diag(beta), split to planes
    {
        const int tr = t >> 3, tc = (t & 7) * 4;
        s16x4 th4, tl4;
#pragma unroll
        for (int e = 0; e < 4; ++e) {
            int j = tc + e;
            float val = ((tr == j) ? 1.f : (tr > j ? A[tr * AP + j] : 0.f)) * sbeta[j];
            unsigned p = split_bf16(val);
            th4[e] = (short)(p >> 16); tl4[e] = (short)(p & 0xffffu);
        }
        *(s16x4*)(Th + tr * PC + tc) = th4;
        *(s16x4*)(Tl + tr * PC + tc) = tl4;
    }
    __syncthreads();

    // u = T'@v (fp32 -> Uws), w = T'@kn (packed -> WP); swapped MFMA + col-major
    {
        const int ci0 = (wv & 1) * 16;
        short8 bTh = fld(Th, ci0, PC, 0, lane);
        short8 bTl = fld(Tl, ci0, PC, 0, lane);
        const int out = wv >> 1;   // 0=u, 1=w
        const short* Ah = out ? knTh : vTh;
        const short* Al = out ? knTl : vTl;
#pragma unroll
        for (int tt = 0; tt < 8; ++tt) {
            int col0 = tt * 16;
            short8 ah = fld(Ah, col0, PC, 0, lane);
            short8 al = fld(Al, col0, PC, 0, lane);
            f32x4 acc = {0.f, 0.f, 0.f, 0.f};
            acc = mf(ah, bTh, mf(ah, bTl, mf(al, bTh, acc)));
            size_t gaddr = base + (size_t)(ci0 + l15) * DK + col0 + quad * 4;
            if (out == 0) {
                *(f32x4*)(Uws + gaddr) = acc;
            } else {
                u32x4 pw;
#pragma unroll
                for (int r = 0; r < 4; ++r) pw[r] = split_bf16(acc[r]);
                *(u32x4*)(WP + gaddr) = pw;
            }
        }
    }
}

// ---------------------------------------------------------------------------
// Kernel 2: sequential chunk scan. 128 blocks = 8 dv-slices x 16 bh.
// 512 threads = 8 waves. 2 barriers/chunk. All C-frag LDS stores packed b64.
// ---------------------------------------------------------------------------
__global__ __launch_bounds__(512, 1) void k_scan(const float* __restrict__ Q,
                                                 const unsigned* __restrict__ KnP,
                                                 const unsigned* __restrict__ WP,
                                                 const float* __restrict__ Uws,
                                                 float* __restrict__ Out,
                                                 float* __restrict__ Sout) {
    __shared__ short qh[C * PK];
    __shared__ short kh[C * PK], kl[C * PK];
    __shared__ short wh[C * PK], wl[C * PK];
    __shared__ short STh[DVB * PK], STl[DVB * PK];   // S^T slice [dv16][dk128]
    __shared__ short kTh[DK * PC], kTl[DK * PC];     // k^T [dk][c]
    __shared__ short uTh[DVB * PC], uTl[DVB * PC];   // u'^T [dv][c]
    __shared__ short ath[C * PC], atl[C * PC];       // attn [ci][cj]

    const int t = threadIdx.x, lane = t & 63, wv = t >> 6;
    const int quad = (t >> 4) & 3, l15 = t & 15;
    const int db = blockIdx.x >> 4, bhi = blockIdx.x & 15;
    const int vcol = db * DVB;
    const size_t bbase = (size_t)bhi * LSEQ * DK;

    short8 Iev, Iod;
    build_ifrags(lane, Iev, Iod);

    const int sr = t >> 4, sc = (t & 15) * 8;   // staging ownership (8 elems)
    const int r0 = (wv & 1) * 16;               // ci tile for wv0/1
    const int dk0 = wv * 16;                    // S-update dk tile per wave

    f32x4 accS = {0.f, 0.f, 0.f, 0.f};          // persistent S[dk][dv] tile

    f32x4 pq0, pq1;
    u32x4 pkn0, pkn1, pw0, pw1;
    float pu[4] = {0.f, 0.f, 0.f, 0.f};

    auto prefetch = [&](int cc) {
        const size_t cb = bbase + (size_t)cc * C * DK;
        pq0 = *(const f32x4*)(Q + cb + 8 * t);
        pq1 = *(const f32x4*)(Q + cb + 8 * t + 4);
        pkn0 = *(const u32x4*)(KnP + cb + 8 * t);
        pkn1 = *(const u32x4*)(KnP + cb + 8 * t + 4);
        pw0 = *(const u32x4*)(WP + cb + 8 * t);
        pw1 = *(const u32x4*)(WP + cb + 8 * t + 4);
        if (wv < 2) {
#pragma unroll
            for (int r = 0; r < 4; ++r)
                pu[r] = Uws[cb + (size_t)(r0 + quad * 4 + r) * DK + vcol + l15];
        }
    };
    auto stage_planes = [&]() {
        float ssq = 0.f;
#pragma unroll
        for (int i = 0; i < 4; ++i) ssq += pq0[i] * pq0[i] + pq1[i] * pq1[i];
        ssq += __shfl_xor(ssq, 1); ssq += __shfl_xor(ssq, 2);
        ssq += __shfl_xor(ssq, 4); ssq += __shfl_xor(ssq, 8);
        const float rq = rsqrtf(ssq + 1e-6f);
        short8 qv;
#pragma unroll
        for (int i = 0; i < 4; ++i) {
            qv[i] = hi_bf16(pq0[i] * rq);
            qv[4 + i] = hi_bf16(pq1[i] * rq);
        }
        *(short8*)(qh + sr * PK + sc) = qv;
        short8 khv, klv, whv, wlv;
#pragma unroll
        for (int i = 0; i < 4; ++i) {
            unsigned p = pkn0[i]; khv[i] = (short)(p >> 16); klv[i] = (short)(p & 0xffffu);
            p = pkn1[i]; khv[4 + i] = (short)(p >> 16); klv[4 + i] = (short)(p & 0xffffu);
            p = pw0[i]; whv[i] = (short)(p >> 16); wlv[i] = (short)(p & 0xffffu);
            p = pw1[i]; whv[4 + i] = (short)(p >> 16); wlv[4 + i] = (short)(p & 0xffffu);
        }
        *(short8*)(kh + sr * PK + sc) = khv;
        *(short8*)(kl + sr * PK + sc) = klv;
        *(short8*)(wh + sr * PK + sc) = whv;
        *(short8*)(wl + sr * PK + sc) = wlv;
    };

    prefetch(0);
    stage_planes();
    for (int e = t; e < DVB * PK; e += 512) { STh[e] = 0; STl[e] = 0; }
    __syncthreads();

    for (int cid = 0; cid < NCH; ++cid) {
        float uc[4] = {pu[0], pu[1], pu[2], pu[3]};
        if (cid + 1 < NCH) prefetch(cid + 1);

        f32x4 oacc = {0.f, 0.f, 0.f, 0.f};   // o^T tile [dv][ci] for wv0/1

        // ===== stage 1: u' (wv0/1, fused q@S), attn (wv2-5), kT (wv6/7) =====
        if (wv < 2) {
            f32x4 uacc = {-uc[0], -uc[1], -uc[2], -uc[3]};   // = w@S - u
#pragma unroll
            for (int ks = 0; ks < 4; ++ks) {
                short8 awh = fld(wh, r0, PK, ks * 32, lane);
                short8 awl = fld(wl, r0, PK, ks * 32, lane);
                short8 bsh = fld(STh, 0, PK, ks * 32, lane);
                short8 bsl = fld(STl, 0, PK, ks * 32, lane);
                short8 aqh = fld(qh, r0, PK, ks * 32, lane);
                uacc = mf(awh, bsh, mf(awh, bsl, mf(awl, bsh, uacc)));
                oacc = mf(bsh, aqh, mf(bsl, aqh, oacc));     // A=S^T,B=q -> C[dv][ci]
            }
            s16x4 uh4, ul4;
#pragma unroll
            for (int r = 0; r < 4; ++r) {
                unsigned p = split_bf16(-uacc[r]);
                uh4[r] = (short)(p >> 16); ul4[r] = (short)(p & 0xffffu);
            }
            *(s16x4*)(uTh + l15 * PC + r0 + quad * 4) = uh4;   // col-major -> u'^T[dv][ci]
            *(s16x4*)(uTl + l15 * PC + r0 + quad * 4) = ul4;
        } else if (wv < 6) {
            const int wa = wv - 2, ci0a = (wa >> 1) * 16, cj0a = (wa & 1) * 16;
            s16x4 ah4 = {0, 0, 0, 0}, al4 = {0, 0, 0, 0};
            if (ci0a >= cj0a) {   // (ci<cj) tile is entirely masked -> store zeros
                f32x4 acc = {0.f, 0.f, 0.f, 0.f};
#pragma unroll
                for (int ks = 0; ks < 4; ++ks) {
                    short8 akh = fld(kh, cj0a, PK, ks * 32, lane);
                    short8 akl = fld(kl, cj0a, PK, ks * 32, lane);
                    short8 bqh = fld(qh, ci0a, PK, ks * 32, lane);
                    acc = mf(akh, bqh, mf(akl, bqh, acc));   // A=k,B=q -> C[cj][ci]
                }
#pragma unroll
                for (int r = 0; r < 4; ++r) {
                    int row = cj0a + quad * 4 + r, col = ci0a + l15;
                    float v = (row <= col) ? acc[r] : 0.f;   // causal
                    unsigned p = split_bf16(v);
                    ah4[r] = (short)(p >> 16); al4[r] = (short)(p & 0xffffu);
                }
            }
            *(s16x4*)(ath + (ci0a + l15) * PC + cj0a + quad * 4) = ah4;  // attn[ci][cj]
            *(s16x4*)(atl + (ci0a + l15) * PC + cj0a + quad * 4) = al4;
        } else {
            const int c0 = (wv - 6) * 16;   // MFMA transpose k -> kT
#pragma unroll
            for (int ks = 0; ks < 4; ++ks) {
#pragma unroll
                for (int pl = 0; pl < 2; ++pl) {
                    short8 fr = fld(pl ? kl : kh, c0, PK, ks * 32, lane);
                    f32x4 z = {0.f, 0.f, 0.f, 0.f};
                    f32x4 cA = mf(fr, Iev, z);
                    f32x4 cB = mf(fr, Iod, z);
                    s16x4 sA, sB;
#pragma unroll
                    for (int r = 0; r < 4; ++r) { sA[r] = trunc_bf16(cA[r]); sB[r] = trunc_bf16(cB[r]); }
                    short* dst = pl ? kTl : kTh;
                    *(s16x4*)(dst + (ks * 32 + l15) * PC + c0 + quad * 4) = sA;
                    *(s16x4*)(dst + (ks * 32 + 16 + l15) * PC + c0 + quad * 4) = sB;
                }
            }
        }
        __syncthreads();

        // ===== stage 2: o finish + write, S accumulate + S plane rewrite,
        //                plane staging for next chunk (S only read in stage 1) =====
        short8 buh = fld(uTh, 0, PC, 0, lane);
        short8 bul = fld(uTl, 0, PC, 0, lane);
        if (wv < 2) {
            short8 bah = fld(ath, r0, PC, 0, lane);
            short8 bal = fld(atl, r0, PC, 0, lane);
            oacc = mf(buh, bah, mf(buh, bal, mf(bul, bah, oacc)));  // A=u'^T,B=attn
            const size_t ob = bbase + (size_t)cid * C * DK;
            *(f32x4*)(Out + ob + (size_t)(r0 + l15) * DK + vcol + quad * 4) = oacc;
        }
        {
            short8 akh = fld(kTh, dk0, PC, 0, lane);
            short8 akl = fld(kTl, dk0, PC, 0, lane);
            accS = mf(akh, buh, mf(akh, bul, mf(akl, buh, accS)));  // C[dk][dv]
        }
        s16x4 sh4, sl4;
#pragma unroll
        for (int r = 0; r < 4; ++r) {
            unsigned p = split_bf16(accS[r]);
            sh4[r] = (short)(p >> 16); sl4[r] = (short)(p & 0xffffu);
        }
        *(s16x4*)(STh + l15 * PK + dk0 + quad * 4) = sh4;   // col-major -> S^T[dv][dk]
        *(s16x4*)(STl + l15 * PK + dk0 + quad * 4) = sl4;
        if (cid + 1 < NCH) stage_planes();
        __syncthreads();
    }

    // final state: Sout[bh][dk][dv]
#pragma unroll
    for (int r = 0; r < 4; ++r)
        Sout[(size_t)bhi * DK * DV + (size_t)(dk0 + quad * 4 + r) * DV + vcol + l15] = accS[r];
}

extern "C" void kernel_launch(void* const* d_in, const int* in_sizes, int n_in,
                              void* d_out, int out_size, void* d_ws, size_t ws_size,
                              hipStream_t stream) {
    const float* Q    = (const float*)d_in[0];
    const float* K    = (const float*)d_in[1];
    const float* V    = (const float*)d_in[2];
    const float* Beta = (const float*)d_in[3];

    float* Out  = (float*)d_out;
    float* Sout = Out + (size_t)BH * LSEQ * DV;

    const size_t NELT = (size_t)BH * LSEQ * DK;   // 8388608
    unsigned* KnP = (unsigned*)d_ws;
    unsigned* WP  = KnP + NELT;
    float*    Uws = (float*)(WP + NELT);          // total ws use: 3*NELT*4B = 100.7 MB

    hipLaunchKernelGGL(k_prep, dim3(BH * NCH), dim3(256), 0, stream,
                       K, V, Beta, KnP, WP, Uws);
    hipLaunchKernelGGL(k_scan, dim3(BH * NDVB), dim3(512), 0, stream,
                       Q, KnP, WP, Uws, Out, Sout);
}

// Round 6
// 357.468 us; speedup vs baseline: 8.8912x; 1.1919x over previous
//
#include <hip/hip_runtime.h>
#include <cstddef>

#define BH   16
#define LSEQ 4096
#define DK   128
#define DV   128
#define C    32
#define NCH  128
#define DVB  16      // dv per scan block
#define NDVB 8
#define PP   136     // prep row-plane pitch (shorts)
#define PC   40      // pitch for [*][32] col planes (kT/vT/T/uT)
#define PS   136     // ST pitch
#define AP   33      // fp32 pitch for 32x32 A

#define NPLANE (2048u * 4096u)   // shorts per [chunk][32][128] plane array
#define NPLAT  (2048u * 1024u)   // shorts per [chunk][32][32] plane array

typedef __attribute__((ext_vector_type(4))) float f32x4;
typedef __attribute__((ext_vector_type(8))) short short8;
typedef __attribute__((ext_vector_type(4))) short s16x4;

// split-bf16: x ~= hi + lo, each bf16 rne. Returns (hi<<16)|lo.
__device__ inline unsigned split_bf16(float x) {
    unsigned u = __builtin_bit_cast(unsigned, x);
    unsigned r = u + 0x7fffu + ((u >> 16) & 1u);
    unsigned h = r >> 16;
    float hf = __builtin_bit_cast(float, r & 0xffff0000u);
    float res = x - hf;
    unsigned u2 = __builtin_bit_cast(unsigned, res);
    unsigned r2 = u2 + 0x7fffu + ((u2 >> 16) & 1u);
    return (h << 16) | (r2 >> 16);
}
__device__ inline short hi_bf16(float x) {
    unsigned u = __builtin_bit_cast(unsigned, x);
    return (short)((u + 0x7fffu + ((u >> 16) & 1u)) >> 16);
}
__device__ inline short trunc_bf16(float x) {   // x already exactly bf16
    return (short)(__builtin_bit_cast(unsigned, x) >> 16);
}

// classic pitched frag load: lane holds P[row0+(lane&15)][k0 + (lane>>4)*8 + j]
__device__ inline short8 fld(const short* P, int row0, int pitch, int k0, int lane) {
    return *(const short8*)(P + (row0 + (lane & 15)) * pitch + k0 + ((lane >> 4) << 3));
}
// swizzled pitch-128 plane frag load ([32][128], chunk c XOR row&7)
__device__ inline short8 fldz128(const short* P, int row0, int ks, int lane) {
    int row = row0 + (lane & 15);
    int c = ks * 4 + (lane >> 4);
    return *(const short8*)(P + row * 128 + ((c ^ (row & 7)) << 3));
}
// swizzled pitch-32 plane frag load ([*][32], chunk c XOR row&3), K=32
__device__ inline short8 fldz32(const short* P, int row0, int lane) {
    int row = row0 + (lane & 15);
    int c = lane >> 4;
    return *(const short8*)(P + row * 32 + ((c ^ (row & 3)) << 3));
}
__device__ inline f32x4 mf(short8 a, short8 b, f32x4 c) {
    return __builtin_amdgcn_mfma_f32_16x16x32_bf16(a, b, c, 0, 0, 0);
}
__device__ inline void build_ifrags(int lane, short8& Iev, short8& Iod) {
    int n = lane & 15, q = lane >> 4;
#pragma unroll
    for (int j = 0; j < 8; ++j) {
        Iev[j] = (q * 8 + j == n)      ? (short)0x3F80 : (short)0;
        Iod[j] = (q * 8 + j == n + 16) ? (short)0x3F80 : (short)0;
    }
}
// global swizzled stores (8B), matching the fldz layouts
__device__ inline void store8_z128(short* Pg, int row, int col0, s16x4 v) {
    int c = col0 >> 3;
    *(s16x4*)(Pg + row * 128 + ((c ^ (row & 7)) << 3) + (col0 & 7)) = v;
}
__device__ inline void store8_z32(short* Pg, int row, int col0, s16x4 v) {
    int c = col0 >> 3;
    *(s16x4*)(Pg + row * 32 + ((c ^ (row & 3)) << 3) + (col0 & 7)) = v;
}
// async global->LDS, 1KB per wave-call (lane i -> ldsbase + i*16)
__device__ inline void dma1k(const short* g, short* l, int lane) {
    __builtin_amdgcn_global_load_lds(
        (const __attribute__((address_space(1))) unsigned int*)(g + lane * 8),
        (__attribute__((address_space(3))) unsigned int*)l, 16, 0, 0);
}

// ---------------------------------------------------------------------------
// Kernel 1: per-chunk precompute. Outputs scan-ready swizzled planes:
//   QH (q l2norm, hi), WH/WL (w split), KTH/KTL (k^T split), ATH/ATL (masked
//   attn = qn@kn^T, split), Uws (fp32).
// ---------------------------------------------------------------------------
__global__ __launch_bounds__(256) void k_prep(const float* __restrict__ Q,
                                              const float* __restrict__ K,
                                              const float* __restrict__ V,
                                              const float* __restrict__ Beta,
                                              short* __restrict__ QHg,
                                              short* __restrict__ WHg,
                                              short* __restrict__ WLg,
                                              short* __restrict__ KTHg,
                                              short* __restrict__ KTLg,
                                              short* __restrict__ ATHg,
                                              short* __restrict__ ATLg,
                                              float* __restrict__ Uws) {
    __shared__ short knh[C * PP], knl[C * PP], vh[C * PP], vl[C * PP], qh[C * PP];
    __shared__ short knTh[DK * PC], knTl[DK * PC], vTh[DK * PC], vTl[DK * PC];
    __shared__ short Th[C * PC], Tl[C * PC];
    __shared__ float A[C * AP];
    __shared__ float sbeta[C];

    const int t = threadIdx.x, lane = t & 63, wv = t >> 6;
    const int quad = (t >> 4) & 3, l15 = t & 15;
    const int g = blockIdx.x;                       // bh*128 + cid
    const size_t base = (size_t)g * (C * DK);
    short8 Iev, Iod;
    build_ifrags(lane, Iev, Iod);

    if (t < C) sbeta[t] = Beta[(size_t)(g >> 7) * LSEQ + (size_t)(g & 127) * C + t];

    // ---- P0: load K,V,Q; norms; write row planes + QH global ----
    const int sr = t >> 3, sc = (t & 7) * 16;
    f32x4 kk[4], vv[4], qq[4];
#pragma unroll
    for (int g4 = 0; g4 < 4; ++g4) {
        kk[g4] = *(const f32x4*)(K + base + 16 * t + 4 * g4);
        vv[g4] = *(const f32x4*)(V + base + 16 * t + 4 * g4);
        qq[g4] = *(const f32x4*)(Q + base + 16 * t + 4 * g4);
    }
    float ssk = 0.f, ssq = 0.f;
#pragma unroll
    for (int g4 = 0; g4 < 4; ++g4) {
#pragma unroll
        for (int e = 0; e < 4; ++e) {
            ssk += kk[g4][e] * kk[g4][e];
            ssq += qq[g4][e] * qq[g4][e];
        }
    }
    ssk += __shfl_xor(ssk, 1); ssk += __shfl_xor(ssk, 2); ssk += __shfl_xor(ssk, 4);
    ssq += __shfl_xor(ssq, 1); ssq += __shfl_xor(ssq, 2); ssq += __shfl_xor(ssq, 4);
    const float rk = rsqrtf(ssk + 1e-6f), rq = rsqrtf(ssq + 1e-6f);
#pragma unroll
    for (int half = 0; half < 2; ++half) {
        short8 h8, l8;
#pragma unroll
        for (int e = 0; e < 8; ++e) {
            unsigned p = split_bf16(kk[2 * half + (e >> 2)][e & 3] * rk);
            h8[e] = (short)(p >> 16); l8[e] = (short)(p & 0xffffu);
        }
        *(short8*)(knh + sr * PP + sc + 8 * half) = h8;
        *(short8*)(knl + sr * PP + sc + 8 * half) = l8;
#pragma unroll
        for (int e = 0; e < 8; ++e) {
            unsigned p = split_bf16(vv[2 * half + (e >> 2)][e & 3]);
            h8[e] = (short)(p >> 16); l8[e] = (short)(p & 0xffffu);
        }
        *(short8*)(vh + sr * PP + sc + 8 * half) = h8;
        *(short8*)(vl + sr * PP + sc + 8 * half) = l8;
        short8 q8;
#pragma unroll
        for (int e = 0; e < 8; ++e) q8[e] = hi_bf16(qq[2 * half + (e >> 2)][e & 3] * rq);
        *(short8*)(qh + sr * PP + sc + 8 * half) = q8;
        int c = (sc >> 3) + half;
        *(short8*)(QHg + (size_t)g * 4096 + sr * 128 + ((c ^ (sr & 7)) << 3)) = q8;
    }
    __syncthreads();

    // ---- P1: G tiles -> A (strict lower, -beta scaled); attn tiles -> ATg ----
    if (wv < 3) {
        const int a0 = (wv == 0) ? 0 : 16;      // m rows (ci for attn)
        const int b0 = (wv == 2) ? 16 : 0;      // n rows (cj for attn)
        f32x4 acc = {0.f, 0.f, 0.f, 0.f};
#pragma unroll
        for (int ks = 0; ks < 4; ++ks) {
            short8 ah = fld(knh, a0, PP, ks * 32, lane);
            short8 al = fld(knl, a0, PP, ks * 32, lane);
            short8 bh_ = fld(knh, b0, PP, ks * 32, lane);
            short8 bl_ = fld(knl, b0, PP, ks * 32, lane);
            acc = mf(ah, bh_, mf(ah, bl_, mf(al, bh_, acc)));
        }
#pragma unroll
        for (int r = 0; r < 4; ++r) {
            int row = a0 + quad * 4 + r, col = b0 + l15;
            A[row * AP + col] = (row > col) ? -sbeta[row] * acc[r] : 0.f;
        }
        // attn tile: A-op = kn rows cj (m=cj), B-op = qh rows ci (n=ci)
        f32x4 at = {0.f, 0.f, 0.f, 0.f};
#pragma unroll
        for (int ks = 0; ks < 4; ++ks) {
            short8 kh_ = fld(knh, b0, PP, ks * 32, lane);
            short8 kl_ = fld(knl, b0, PP, ks * 32, lane);
            short8 qf = fld(qh, a0, PP, ks * 32, lane);
            at = mf(kh_, qf, mf(kl_, qf, at));
        }
        s16x4 h4, l4;
#pragma unroll
        for (int r = 0; r < 4; ++r) {
            int cj = b0 + quad * 4 + r, ci = a0 + l15;
            float v = (cj <= ci) ? at[r] : 0.f;
            unsigned p = split_bf16(v);
            h4[r] = (short)(p >> 16); l4[r] = (short)(p & 0xffffu);
        }
        store8_z32(ATHg + (size_t)g * 1024, a0 + l15, b0 + quad * 4, h4);
        store8_z32(ATLg + (size_t)g * 1024, a0 + l15, b0 + quad * 4, l4);
    } else {
        // zero the (rows 0-15, cols 16-31) upper tile of A and attn
#pragma unroll
        for (int r = 0; r < 4; ++r) A[l15 * AP + 16 + quad * 4 + r] = 0.f;
        s16x4 z = {0, 0, 0, 0};
        store8_z32(ATHg + (size_t)g * 1024, l15, 16 + quad * 4, z);
        store8_z32(ATLg + (size_t)g * 1024, l15, 16 + quad * 4, z);
    }
    __syncthreads();

    // ---- P2: transposes (LDS + KT global) on wv0-2; substitution on wv3 ----
    auto tplane = [&](const short* src, short* dst, short* gdst) {
#pragma unroll
        for (int c0 = 0; c0 <= 16; c0 += 16) {
#pragma unroll
            for (int ks = 0; ks < 4; ++ks) {
                short8 fr = fld(src, c0, PP, ks * 32, lane);
                f32x4 z = {0.f, 0.f, 0.f, 0.f};
                f32x4 cA = mf(fr, Iev, z);
                f32x4 cB = mf(fr, Iod, z);
                s16x4 sA, sB;
#pragma unroll
                for (int r = 0; r < 4; ++r) { sA[r] = trunc_bf16(cA[r]); sB[r] = trunc_bf16(cB[r]); }
                *(s16x4*)(dst + (ks * 32 + l15) * PC + c0 + quad * 4) = sA;
                *(s16x4*)(dst + (ks * 32 + 16 + l15) * PC + c0 + quad * 4) = sB;
                if (gdst) {
                    store8_z32(gdst, ks * 32 + l15, c0 + quad * 4, sA);
                    store8_z32(gdst, ks * 32 + 16 + l15, c0 + quad * 4, sB);
                }
            }
        }
    };
    if (wv == 0) {
        tplane(knh, knTh, KTHg + (size_t)g * 4096);
        tplane(vl, vTl, nullptr);
    } else if (wv == 1) {
        tplane(knl, knTl, KTLg + (size_t)g * 4096);
    } else if (wv == 2) {
        tplane(vh, vTh, nullptr);
    } else if (lane < C) {
        const int j = lane;       // forward substitution (upper of A is zero)
        for (int i = 1; i < C; ++i) {
            float upd = 0.f;
            for (int kk2 = 1; kk2 < i; ++kk2) upd += A[i * AP + kk2] * A[kk2 * AP + j];
            if (j < i) A[i * AP + j] += upd;
        }
    }
    __syncthreads();

    // ---- P3: T' = (A + I) * diag(beta) -> Th/Tl ----
    {
        int tr = t >> 3, tc = (t & 7) * 4;
        s16x4 h4, l4;
#pragma unroll
        for (int e = 0; e < 4; ++e) {
            int j = tc + e;
            float val = ((tr == j) ? 1.f : (tr > j ? A[tr * AP + j] : 0.f)) * sbeta[j];
            unsigned p = split_bf16(val);
            h4[e] = (short)(p >> 16); l4[e] = (short)(p & 0xffffu);
        }
        *(s16x4*)(Th + tr * PC + tc) = h4;
        *(s16x4*)(Tl + tr * PC + tc) = l4;
    }
    __syncthreads();

    // ---- P4: u = T'@v (fp32 -> Uws), w = T'@kn (split -> WH/WL planes) ----
    {
        const int ci0 = (wv & 1) * 16;
        short8 bTh = fld(Th, ci0, PC, 0, lane);
        short8 bTl = fld(Tl, ci0, PC, 0, lane);
        if (wv < 2) {
#pragma unroll
            for (int tt = 0; tt < 8; ++tt) {
                short8 ah = fld(vTh, tt * 16, PC, 0, lane);
                short8 al = fld(vTl, tt * 16, PC, 0, lane);
                f32x4 z = {0.f, 0.f, 0.f, 0.f};
                f32x4 acc = mf(ah, bTh, mf(ah, bTl, mf(al, bTh, z)));
                *(f32x4*)(Uws + (size_t)g * 4096 + (size_t)(ci0 + l15) * DK + tt * 16 + quad * 4) = acc;
            }
        } else {
#pragma unroll
            for (int tt = 0; tt < 8; ++tt) {
                short8 ah = fld(knTh, tt * 16, PC, 0, lane);
                short8 al = fld(knTl, tt * 16, PC, 0, lane);
                f32x4 z = {0.f, 0.f, 0.f, 0.f};
                f32x4 acc = mf(ah, bTh, mf(ah, bTl, mf(al, bTh, z)));
                s16x4 h4, l4;
#pragma unroll
                for (int r = 0; r < 4; ++r) {
                    unsigned p = split_bf16(acc[r]);
                    h4[r] = (short)(p >> 16); l4[r] = (short)(p & 0xffffu);
                }
                store8_z128(WHg + (size_t)g * 4096, ci0 + l15, tt * 16 + quad * 4, h4);
                store8_z128(WLg + (size_t)g * 4096, ci0 + l15, tt * 16 + quad * 4, l4);
            }
        }
    }
}

// ---------------------------------------------------------------------------
// Kernel 2: sequential chunk scan. 128 blocks = 8 dv-slices x 16 bh, 8 waves.
// All S-independent inputs DMA'd via global_load_lds (double-buffered).
// ---------------------------------------------------------------------------
__global__ __launch_bounds__(512, 1) void k_scan(const short* __restrict__ QHg,
                                                 const short* __restrict__ WHg,
                                                 const short* __restrict__ WLg,
                                                 const short* __restrict__ KTHg,
                                                 const short* __restrict__ KTLg,
                                                 const short* __restrict__ ATHg,
                                                 const short* __restrict__ ATLg,
                                                 const float* __restrict__ Uws,
                                                 float* __restrict__ Out,
                                                 float* __restrict__ Sout) {
    __shared__ short bQ[2][4096], bWH[2][4096], bWL[2][4096], bKTH[2][4096], bKTL[2][4096];
    __shared__ short bATH[2][1024], bATL[2][1024];
    __shared__ short STh[DVB * PS], STl[DVB * PS];
    __shared__ short uTh[DVB * PC], uTl[DVB * PC];

    const int t = threadIdx.x, lane = t & 63, wv = t >> 6;
    const int quad = (t >> 4) & 3, l15 = t & 15;
    const int db = blockIdx.x >> 4, bhi = blockIdx.x & 15;
    const int vcol = db * DVB;
    const int r0 = (wv & 1) * 16;          // ci tile for wv0/1
    const int dk0 = wv * 16;               // S dk-tile per wave
    const size_t gb = (size_t)bhi * NCH;   // chunk index base

    f32x4 accS = {0.f, 0.f, 0.f, 0.f};
    float pu[4] = {0.f, 0.f, 0.f, 0.f};

    auto dma_chunk = [&](int cc, int s) {
        const size_t go = (gb + cc) * 4096;
        dma1k(QHg + go + wv * 512, &bQ[s][wv * 512], lane);
        dma1k(WHg + go + wv * 512, &bWH[s][wv * 512], lane);
        dma1k(WLg + go + wv * 512, &bWL[s][wv * 512], lane);
        dma1k(KTHg + go + wv * 512, &bKTH[s][wv * 512], lane);
        dma1k(KTLg + go + wv * 512, &bKTL[s][wv * 512], lane);
        if (wv < 4) {
            const size_t ga = (gb + cc) * 1024 + (size_t)(wv & 1) * 512;
            if (wv < 2) dma1k(ATHg + ga, &bATH[s][(wv & 1) * 512], lane);
            else        dma1k(ATLg + ga, &bATL[s][(wv & 1) * 512], lane);
        }
    };
    auto pref_u = [&](int cc) {
        if (wv < 2) {
            const size_t ub = (gb + cc) * 4096;
#pragma unroll
            for (int r = 0; r < 4; ++r)
                pu[r] = Uws[ub + (size_t)(r0 + quad * 4 + r) * DK + vcol + l15];
        }
    };

    for (int e = t; e < DVB * PS; e += 512) { STh[e] = 0; STl[e] = 0; }
    dma_chunk(0, 0);
    pref_u(0);
    __syncthreads();   // drains DMA(0)

    for (int cid = 0; cid < NCH; ++cid) {
        const int cur = cid & 1;
        f32x4 oc = {0.f, 0.f, 0.f, 0.f};

        // ---- stage 1: u' = u - w@S and o1 = q@S (wv0/1 only) ----
        if (wv < 2) {
            f32x4 u0 = {-pu[0], -pu[1], -pu[2], -pu[3]};
            f32x4 u1 = {0.f, 0.f, 0.f, 0.f}, u2 = {0.f, 0.f, 0.f, 0.f};
            f32x4 o1 = {0.f, 0.f, 0.f, 0.f};
#pragma unroll
            for (int ks = 0; ks < 4; ++ks) {
                short8 wh_ = fldz128(bWH[cur], r0, ks, lane);
                short8 wl_ = fldz128(bWL[cur], r0, ks, lane);
                short8 sh_ = fld(STh, 0, PS, ks * 32, lane);
                short8 sl_ = fld(STl, 0, PS, ks * 32, lane);
                short8 qf = fldz128(bQ[cur], r0, ks, lane);
                u0 = mf(wh_, sh_, u0);          // independent chains
                u1 = mf(wh_, sl_, u1);
                u2 = mf(wl_, sh_, u2);
                oc = mf(sh_, qf, oc);           // o^T[dv][ci]
                o1 = mf(sl_, qf, o1);
            }
            oc += o1;
            f32x4 us = u0 + u1 + u2;            // = w@S - u
            s16x4 h4, l4;
#pragma unroll
            for (int r = 0; r < 4; ++r) {
                unsigned p = split_bf16(-us[r]);
                h4[r] = (short)(p >> 16); l4[r] = (short)(p & 0xffffu);
            }
            *(s16x4*)(uTh + l15 * PC + r0 + quad * 4) = h4;   // u'^T[dv][c]
            *(s16x4*)(uTl + l15 * PC + r0 + quad * 4) = l4;
        }
        __syncthreads();

        // ---- stage 2: o finish + S accumulate + S replanes + next DMA ----
        short8 buh = fld(uTh, 0, PC, 0, lane);
        short8 bul = fld(uTl, 0, PC, 0, lane);
        if (wv < 2) {
            short8 bah = fldz32(bATH[cur], r0, lane);
            short8 bal = fldz32(bATL[cur], r0, lane);
            oc = mf(buh, bah, mf(buh, bal, mf(bul, bah, oc)));
            const size_t ob = ((size_t)bhi * LSEQ + (size_t)cid * C) * DK;
            *(f32x4*)(Out + ob + (size_t)(r0 + l15) * DK + vcol + quad * 4) = oc;
        }
        {
            short8 kth = fldz32(bKTH[cur], dk0, lane);
            short8 ktl = fldz32(bKTL[cur], dk0, lane);
            f32x4 z = {0.f, 0.f, 0.f, 0.f};
            f32x4 tband = mf(kth, bul, mf(ktl, buh, z));
            accS = mf(kth, buh, accS);
            accS += tband;
            s16x4 h4, l4;
#pragma unroll
            for (int r = 0; r < 4; ++r) {
                unsigned p = split_bf16(accS[r]);
                h4[r] = (short)(p >> 16); l4[r] = (short)(p & 0xffffu);
            }
            *(s16x4*)(STh + l15 * PS + dk0 + quad * 4) = h4;   // S^T[dv][dk]
            *(s16x4*)(STl + l15 * PS + dk0 + quad * 4) = l4;
        }
        if (cid + 1 < NCH) {
            dma_chunk(cid + 1, cur ^ 1);
            pref_u(cid + 1);
        }
        __syncthreads();
    }

    // final state: Sout[bh][dk][dv]
#pragma unroll
    for (int r = 0; r < 4; ++r)
        Sout[(size_t)bhi * DK * DV + (size_t)(dk0 + quad * 4 + r) * DV + vcol + l15] = accS[r];
}

extern "C" void kernel_launch(void* const* d_in, const int* in_sizes, int n_in,
                              void* d_out, int out_size, void* d_ws, size_t ws_size,
                              hipStream_t stream) {
    const float* Q    = (const float*)d_in[0];
    const float* K    = (const float*)d_in[1];
    const float* V    = (const float*)d_in[2];
    const float* Beta = (const float*)d_in[3];

    float* Out  = (float*)d_out;
    float* Sout = Out + (size_t)BH * LSEQ * DV;

    short* QHg  = (short*)d_ws;
    short* WHg  = QHg + NPLANE;
    short* WLg  = WHg + NPLANE;
    short* KTHg = WLg + NPLANE;
    short* KTLg = KTHg + NPLANE;
    short* ATHg = KTLg + NPLANE;
    short* ATLg = ATHg + NPLAT;
    float* Uws  = (float*)(ATLg + NPLAT);   // total ws: 120 MiB

    hipLaunchKernelGGL(k_prep, dim3(BH * NCH), dim3(256), 0, stream,
                       Q, K, V, Beta, QHg, WHg, WLg, KTHg, KTLg, ATHg, ATLg, Uws);
    hipLaunchKernelGGL(k_scan, dim3(BH * NDVB), dim3(512), 0, stream,
                       QHg, WHg, WLg, KTHg, KTLg, ATHg, ATLg, Uws, Out, Sout);
}